// Round 18
// baseline (136.891 us; speedup 1.0000x reference)
//
#include <hip/hip_runtime.h>
#include <hip/hip_bf16.h>

#define N_ROWS 8192
#define N_HALF 4096
#define DIM    2048
#define ROWB   2048       // bytes per z row (fp8, plain row-major)
#define INV_T  2.0f
#define QSCL   64.0f      // z scaled by 64 before fp8 quant
#define SIMSCL 0.00048828125f  // INV_T / (QSCL*QSCL) = 2/4096
#define SCONE  0x7F7F7F7F // E8M0 unit scales (2^0) for all blocks
#define NG1    1024       // full tiles: sum_{bi}(63-2*bi), bj in [2bi,63)
#define NG2    128        // tail: 32 bj=63 tiles M-split x4 (64-row blocks)
#define NKT    32         // DIM/64 K-tiles

typedef __attribute__((ext_vector_type(4)))  float f32x4;
typedef __attribute__((ext_vector_type(16))) float f32x16;
typedef __attribute__((ext_vector_type(4)))  int   i32x4;
typedef __attribute__((ext_vector_type(8)))  int   i32x8;

__device__ __forceinline__ void gload_lds16(const void* g, void* l) {
  __builtin_amdgcn_global_load_lds(
      (const __attribute__((address_space(1))) unsigned int*)g,
      (__attribute__((address_space(3))) unsigned int*)l, 16, 0, 0);
}

// ---------------------------------------------------------------------------
// Kernel 1: fused normalize + fp8-quantize + positives + self-dots + denom=0.
// zq plain row-major (k-linear).  pos from fp32 normalized values; selfd
// from DECODED fp8 (consistent with the unit-scale MFMA diagonal).
// ---------------------------------------------------------------------------
__global__ __launch_bounds__(256) void normpos_k(
    const float* __restrict__ xi, const float* __restrict__ xj,
    char* __restrict__ zq, float* __restrict__ pos,
    float* __restrict__ selfd, float* __restrict__ denom)
{
  const int b = blockIdx.x;            // 0..4095
  const int t = threadIdx.x;
  const float4* si = (const float4*)(xi + (size_t)b * DIM);
  const float4* sj = (const float4*)(xj + (size_t)b * DIM);
  float4 a0 = si[t * 2], a1 = si[t * 2 + 1];
  float4 c0 = sj[t * 2], c1 = sj[t * 2 + 1];
  float ssi = a0.x*a0.x + a0.y*a0.y + a0.z*a0.z + a0.w*a0.w
            + a1.x*a1.x + a1.y*a1.y + a1.z*a1.z + a1.w*a1.w;
  float ssj = c0.x*c0.x + c0.y*c0.y + c0.z*c0.z + c0.w*c0.w
            + c1.x*c1.x + c1.y*c1.y + c1.z*c1.z + c1.w*c1.w;
  #pragma unroll
  for (int m = 1; m < 64; m <<= 1) {
    ssi += __shfl_xor(ssi, m, 64);
    ssj += __shfl_xor(ssj, m, 64);
  }
  __shared__ float ri[4], rj[4];
  if ((t & 63) == 0) { ri[t >> 6] = ssi; rj[t >> 6] = ssj; }
  __syncthreads();
  float sci = 1.0f / fmaxf(sqrtf(ri[0] + ri[1] + ri[2] + ri[3]), 1e-12f);
  float scj = 1.0f / fmaxf(sqrtf(rj[0] + rj[1] + rj[2] + rj[3]), 1e-12f);

  float fi[8] = {a0.x, a0.y, a0.z, a0.w, a1.x, a1.y, a1.z, a1.w};
  float fj[8] = {c0.x, c0.y, c0.z, c0.w, c1.x, c1.y, c1.z, c1.w};
  float ni[8], nj[8];
  float dp = 0.f;
  #pragma unroll
  for (int e = 0; e < 8; ++e) {
    ni[e] = fi[e] * sci;
    nj[e] = fj[e] * scj;
    dp += ni[e] * nj[e];                 // fp32 positive-pair sim
  }
  int wi0 = 0, wi1 = 0, wj0 = 0, wj1 = 0;
  wi0 = __builtin_amdgcn_cvt_pk_fp8_f32(ni[0]*QSCL, ni[1]*QSCL, wi0, false);
  wi0 = __builtin_amdgcn_cvt_pk_fp8_f32(ni[2]*QSCL, ni[3]*QSCL, wi0, true);
  wi1 = __builtin_amdgcn_cvt_pk_fp8_f32(ni[4]*QSCL, ni[5]*QSCL, wi1, false);
  wi1 = __builtin_amdgcn_cvt_pk_fp8_f32(ni[6]*QSCL, ni[7]*QSCL, wi1, true);
  wj0 = __builtin_amdgcn_cvt_pk_fp8_f32(nj[0]*QSCL, nj[1]*QSCL, wj0, false);
  wj0 = __builtin_amdgcn_cvt_pk_fp8_f32(nj[2]*QSCL, nj[3]*QSCL, wj0, true);
  wj1 = __builtin_amdgcn_cvt_pk_fp8_f32(nj[4]*QSCL, nj[5]*QSCL, wj1, false);
  wj1 = __builtin_amdgcn_cvt_pk_fp8_f32(nj[6]*QSCL, nj[7]*QSCL, wj1, true);
  ((int2*)(zq + (size_t)b * ROWB))[t]            = make_int2(wi0, wi1);
  ((int2*)(zq + (size_t)(b + N_HALF) * ROWB))[t] = make_int2(wj0, wj1);

  float dsi = 0.f, dsj = 0.f;
  {
    float d;
    d = __builtin_amdgcn_cvt_f32_fp8(wi0, 0); dsi += d * d;
    d = __builtin_amdgcn_cvt_f32_fp8(wi0, 1); dsi += d * d;
    d = __builtin_amdgcn_cvt_f32_fp8(wi0, 2); dsi += d * d;
    d = __builtin_amdgcn_cvt_f32_fp8(wi0, 3); dsi += d * d;
    d = __builtin_amdgcn_cvt_f32_fp8(wi1, 0); dsi += d * d;
    d = __builtin_amdgcn_cvt_f32_fp8(wi1, 1); dsi += d * d;
    d = __builtin_amdgcn_cvt_f32_fp8(wi1, 2); dsi += d * d;
    d = __builtin_amdgcn_cvt_f32_fp8(wi1, 3); dsi += d * d;
    d = __builtin_amdgcn_cvt_f32_fp8(wj0, 0); dsj += d * d;
    d = __builtin_amdgcn_cvt_f32_fp8(wj0, 1); dsj += d * d;
    d = __builtin_amdgcn_cvt_f32_fp8(wj0, 2); dsj += d * d;
    d = __builtin_amdgcn_cvt_f32_fp8(wj0, 3); dsj += d * d;
    d = __builtin_amdgcn_cvt_f32_fp8(wj1, 0); dsj += d * d;
    d = __builtin_amdgcn_cvt_f32_fp8(wj1, 1); dsj += d * d;
    d = __builtin_amdgcn_cvt_f32_fp8(wj1, 2); dsj += d * d;
    d = __builtin_amdgcn_cvt_f32_fp8(wj1, 3); dsj += d * d;
  }
  #pragma unroll
  for (int m = 1; m < 64; m <<= 1) {
    dp  += __shfl_xor(dp, m, 64);
    dsi += __shfl_xor(dsi, m, 64);
    dsj += __shfl_xor(dsj, m, 64);
  }
  __shared__ float rp[4], rsi[4], rsj[4];
  if ((t & 63) == 0) { rp[t >> 6] = dp; rsi[t >> 6] = dsi; rsj[t >> 6] = dsj; }
  __syncthreads();
  if (t == 0) {
    float p = rp[0] + rp[1] + rp[2] + rp[3];
    pos[b]            = p;
    pos[b + N_HALF]   = p;
    selfd[b]          = rsi[0] + rsi[1] + rsi[2] + rsi[3];
    selfd[b + N_HALF] = rsj[0] + rsj[1] + rsj[2] + rsj[3];
    denom[b]          = 0.f;
    denom[b + N_HALF] = 0.f;
  }
}

// ---------------------------------------------------------------------------
// Kernel 2: MX-scaled fp8 symmetric sim-tile + exp row/col sums, BK=64.
// mfma_scale_f32_32x32x64_f8f6f4 with unit E8M0 scales (= plain fp8 dot at
// 2.29x the non-scaled rate).  Operand layout: lane l holds k-contiguous
// 32B, k = (l>>5)*32 + e (e = byte index); read as 2 swizzled ds_read_b128.
// Grid: 1024 full 256x128 tiles (2 clean rounds, 2 blk/CU) + 128 tail
// (64x128, M-split x4 of the bj=63 tiles).  8 waves: full = 4M x 2N with
// per-wave 64x64 (2x2 32-frags); tail = 2M x 4N, 1 frag/wave.
// LDS: 3-slot lead-2 (A 16K + B 8K = 72 KiB), STAGE = 3 uniform calls/wave
// -> steady vmcnt(3), final vmcnt(0).  LDS row q (128 B) = tile rows 2q,
// 2q+1; 16B slot s = ((r&1)*4 + c) ^ (q&7), c = k-chunk 0..3; staged via
// inverse-swizzled global source (linear gload dest).  Bank-audit: every
// 16-lane read phase = 2 lanes/slot = free 2-way.
// C/D (32x32): col = lane&31, row = (reg&3) + 8*(reg>>2) + 4*(lane>>5).
// ---------------------------------------------------------------------------
__global__ __launch_bounds__(512, 4) void simexp_k(
    const char* __restrict__ zq, float* __restrict__ denom)
{
  __shared__ char lds[73728];
  char* ldsA = lds;            // 3 x 16384 (tail: 3 x 4096)
  char* ldsB = lds + 49152;    // 3 x 8192

  const int t    = threadIdx.x;
  const int wave = t >> 6, lane = t & 63;
  const int h    = lane >> 5;          // k-half 0..1
  const int bid  = blockIdx.x;

  // staging-source decomposition (inverse of linear LDS dest)
  const int sqq = t >> 3;              // LDS row (per 8 KiB call)
  const int s0  = (t & 7) ^ (sqq & 7);
  const int srr = s0 >> 2;             // row parity
  const int so  = s0 & 3;              // k-chunk

  if (bid < NG1) {
    // ===================== FULL 256x128 TILE PATH ========================
    const int wr = wave >> 1, wc = wave & 1;   // 4M x 2N

    int rem = (bid & 7) * (NG1 / 8) + (bid >> 3);   // XCD-bijective
    int bi = 0;
    while (rem >= 63 - 2 * bi) { rem -= 63 - 2 * bi; ++bi; }
    const int bj   = 2 * bi + rem;               // in [2bi, 63)
    const int row0 = bi * 256;
    const int col0 = bj * 128;

    const char* srcA0 = zq + (size_t)(row0 + 2 * sqq + srr) * ROWB + so * 16;
    const char* srcA1 = srcA0 + (size_t)128 * ROWB;
    const char* srcB  = zq + (size_t)(col0 + 2 * sqq + srr) * ROWB + so * 16;
    char* dA = ldsA + wave * 1024;
    char* dB = ldsB + wave * 1024;

    int offA[2][2], offB[2][2];
    #pragma unroll
    for (int m = 0; m < 2; ++m)
      #pragma unroll
      for (int j = 0; j < 2; ++j) {
        int r = wr * 64 + m * 32 + (lane & 31);
        int q = r >> 1, c = h * 2 + j;
        offA[m][j] = q * 128 + ((((r & 1) * 4 + c) ^ (q & 7)) << 4);
      }
    #pragma unroll
    for (int n = 0; n < 2; ++n)
      #pragma unroll
      for (int j = 0; j < 2; ++j) {
        int r = wc * 64 + n * 32 + (lane & 31);
        int q = r >> 1, c = h * 2 + j;
        offB[n][j] = q * 128 + ((((r & 1) * 4 + c) ^ (q & 7)) << 4);
      }

    f32x16 acc[2][2] = {};

#define STAGE(kt, slot) do {                                   \
      gload_lds16(srcA0 + (kt) * 64, dA + (slot) * 16384);     \
      gload_lds16(srcA1 + (kt) * 64, dA + (slot) * 16384 + 8192); \
      gload_lds16(srcB  + (kt) * 64, dB + (slot) * 8192);      \
    } while (0)

    STAGE(0, 0);
    STAGE(1, 1);

    int sl = 0;
    for (int p = 0; p < NKT; ++p) {
      if (p < NKT - 1) asm volatile("s_waitcnt vmcnt(3)" ::: "memory");
      else             asm volatile("s_waitcnt vmcnt(0)" ::: "memory");
      __builtin_amdgcn_s_barrier();
      __builtin_amdgcn_sched_barrier(0);

      const char* Ab = ldsA + sl * 16384;
      const char* Bb = ldsB + sl * 8192;
      i32x8 a[2], b[2];
      #pragma unroll
      for (int m = 0; m < 2; ++m) {
        i32x4 lo = *(const i32x4*)(Ab + offA[m][0]);
        i32x4 hi = *(const i32x4*)(Ab + offA[m][1]);
        a[m] = __builtin_shufflevector(lo, hi, 0, 1, 2, 3, 4, 5, 6, 7);
      }
      #pragma unroll
      for (int n = 0; n < 2; ++n) {
        i32x4 lo = *(const i32x4*)(Bb + offB[n][0]);
        i32x4 hi = *(const i32x4*)(Bb + offB[n][1]);
        b[n] = __builtin_shufflevector(lo, hi, 0, 1, 2, 3, 4, 5, 6, 7);
      }

      if (p + 2 < NKT) {
        int s2 = sl + 2; if (s2 >= 3) s2 -= 3;
        STAGE(p + 2, s2);
      }

      __builtin_amdgcn_s_setprio(1);
      #pragma unroll
      for (int m = 0; m < 2; ++m)
        #pragma unroll
        for (int n = 0; n < 2; ++n)
          acc[m][n] = __builtin_amdgcn_mfma_scale_f32_32x32x64_f8f6f4(
              a[m], b[n], acc[m][n], 0, 0, 0, SCONE, 0, SCONE);
      __builtin_amdgcn_s_setprio(0);
      __builtin_amdgcn_sched_barrier(0);

      if (++sl >= 3) sl = 0;
    }
#undef STAGE

    #pragma unroll
    for (int m = 0; m < 2; ++m)
      #pragma unroll
      for (int n = 0; n < 2; ++n)
        #pragma unroll
        for (int r = 0; r < 16; ++r)
          acc[m][n][r] = __expf(acc[m][n][r] * SIMSCL);

    // row sums: col = lane&31; row = (reg&3)+8*(reg>>2)+4*(lane>>5)
    #pragma unroll
    for (int m = 0; m < 2; ++m) {
      #pragma unroll
      for (int r = 0; r < 16; ++r) {
        float s = acc[m][0][r] + acc[m][1][r];
        s += __shfl_xor(s, 1, 64);
        s += __shfl_xor(s, 2, 64);
        s += __shfl_xor(s, 4, 64);
        s += __shfl_xor(s, 8, 64);
        s += __shfl_xor(s, 16, 64);
        if ((lane & 31) == 0) {
          int grow = row0 + wr * 64 + m * 32 + (r & 3) + 8 * (r >> 2) + 4 * h;
          atomicAdd(&denom[grow], s);
        }
      }
    }

    if (bj >= 2 * bi + 2) {
      #pragma unroll
      for (int n = 0; n < 2; ++n) {
        float cs = 0.f;
        #pragma unroll
        for (int m = 0; m < 2; ++m)
          #pragma unroll
          for (int r = 0; r < 16; ++r)
            cs += acc[m][n][r];
        cs += __shfl_xor(cs, 32, 64);
        if (lane < 32) {
          int gcol = col0 + wc * 64 + n * 32 + lane;
          atomicAdd(&denom[gcol], cs);
        }
      }
    }
  } else {
    // ===================== TAIL PATH: 64-row x 128-col, cols 8064 ========
    const int sub  = bid - NG1;                // 0..127
    const int bi   = sub >> 2;                 // band 0..31
    const int row0 = bi * 256 + (sub & 3) * 64;
    const int col0 = 8064;
    const int wr   = wave >> 2, wc = wave & 3; // 2M x 4N, 1 frag/wave

    const char* srcB = zq + (size_t)(col0 + 2 * sqq + srr) * ROWB + so * 16;
    // A: 4 KiB staged by waves 0-3 (t<256): q = (t&255)>>3 in 0..31
    const int tA   = t & 255;
    const int sqA  = tA >> 3;
    const int s0A  = (tA & 7) ^ (sqA & 7);
    const char* srcAs = zq + (size_t)(row0 + 2 * sqA + (s0A >> 2)) * ROWB
                      + (s0A & 3) * 16;

    int offA2[2], offB2[2];
    #pragma unroll
    for (int j = 0; j < 2; ++j) {
      int r = wr * 32 + (lane & 31);           // 0..63
      int q = r >> 1, c = h * 2 + j;
      offA2[j] = q * 128 + ((((r & 1) * 4 + c) ^ (q & 7)) << 4);
    }
    #pragma unroll
    for (int j = 0; j < 2; ++j) {
      int r = wc * 32 + (lane & 31);           // 0..127
      int q = r >> 1, c = h * 2 + j;
      offB2[j] = q * 128 + ((((r & 1) * 4 + c) ^ (q & 7)) << 4);
    }

    f32x16 acc2 = {};

#define STAGE_T(kt, slot) do {                                            \
      gload_lds16(srcB + (kt) * 64, ldsB + (slot) * 8192 + wave * 1024);  \
      if (wave < 4)                                                       \
        gload_lds16(srcAs + (kt) * 64,                                    \
                    ldsA + (slot) * 4096 + wave * 1024);                  \
    } while (0)

    STAGE_T(0, 0);
    STAGE_T(1, 1);

    int sl = 0;
    for (int p = 0; p < NKT; ++p) {
      if (p < NKT - 1) {
        if (wave < 4) asm volatile("s_waitcnt vmcnt(2)" ::: "memory");
        else          asm volatile("s_waitcnt vmcnt(1)" ::: "memory");
      } else {
        asm volatile("s_waitcnt vmcnt(0)" ::: "memory");
      }
      __builtin_amdgcn_s_barrier();
      __builtin_amdgcn_sched_barrier(0);

      const char* Ab = ldsA + sl * 4096;
      const char* Bb = ldsB + sl * 8192;
      i32x4 alo = *(const i32x4*)(Ab + offA2[0]);
      i32x4 ahi = *(const i32x4*)(Ab + offA2[1]);
      i32x4 blo = *(const i32x4*)(Bb + offB2[0]);
      i32x4 bhi = *(const i32x4*)(Bb + offB2[1]);
      i32x8 a = __builtin_shufflevector(alo, ahi, 0, 1, 2, 3, 4, 5, 6, 7);
      i32x8 b = __builtin_shufflevector(blo, bhi, 0, 1, 2, 3, 4, 5, 6, 7);

      if (p + 2 < NKT) {
        int s2 = sl + 2; if (s2 >= 3) s2 -= 3;
        STAGE_T(p + 2, s2);
      }

      __builtin_amdgcn_s_setprio(1);
      acc2 = __builtin_amdgcn_mfma_scale_f32_32x32x64_f8f6f4(
          a, b, acc2, 0, 0, 0, SCONE, 0, SCONE);
      __builtin_amdgcn_s_setprio(0);
      __builtin_amdgcn_sched_barrier(0);

      if (++sl >= 3) sl = 0;
    }
#undef STAGE_T

    #pragma unroll
    for (int r = 0; r < 16; ++r)
      acc2[r] = __expf(acc2[r] * SIMSCL);

    // row sums
    #pragma unroll
    for (int r = 0; r < 16; ++r) {
      float s = acc2[r];
      s += __shfl_xor(s, 1, 64);
      s += __shfl_xor(s, 2, 64);
      s += __shfl_xor(s, 4, 64);
      s += __shfl_xor(s, 8, 64);
      s += __shfl_xor(s, 16, 64);
      if ((lane & 31) == 0) {
        int grow = row0 + wr * 32 + (r & 3) + 8 * (r >> 2) + 4 * h;
        atomicAdd(&denom[grow], s);
      }
    }

    // col sums — strip right of band diag for bi <= 30
    if (bi <= 30) {
      float cs = 0.f;
      #pragma unroll
      for (int r = 0; r < 16; ++r) cs += acc2[r];
      cs += __shfl_xor(cs, 32, 64);
      if (lane < 32) {
        int gcol = col0 + wc * 32 + lane;
        atomicAdd(&denom[gcol], cs);
      }
    }
  }
}

// ---------------------------------------------------------------------------
// Kernel 3: loss = mean_i( log(denom_i - exp(self_i*SIMSCL)) - pos_i*INV_T )
// ---------------------------------------------------------------------------
__global__ __launch_bounds__(256) void loss_k(
    const float* __restrict__ denom, const float* __restrict__ pos,
    const float* __restrict__ selfd, float* __restrict__ out)
{
  const int t = threadIdx.x;
  float acc = 0.f;
  for (int i = t; i < N_ROWS; i += 256) {
    float d = denom[i] - __expf(selfd[i] * SIMSCL);
    acc += __logf(d) - pos[i] * INV_T;
  }
  #pragma unroll
  for (int m = 1; m < 64; m <<= 1) acc += __shfl_xor(acc, m, 64);
  __shared__ float red[4];
  if ((t & 63) == 0) red[t >> 6] = acc;
  __syncthreads();
  if (t == 0) out[0] = (red[0] + red[1] + red[2] + red[3]) / (float)N_ROWS;
}

// ---------------------------------------------------------------------------
extern "C" void kernel_launch(void* const* d_in, const int* in_sizes, int n_in,
                              void* d_out, int out_size, void* d_ws, size_t ws_size,
                              hipStream_t stream) {
  const float* xi = (const float*)d_in[0];
  const float* xj = (const float*)d_in[1];
  float* out = (float*)d_out;

  char*  ws    = (char*)d_ws;
  char*  zq    = ws;                                           // 16 MiB fp8 z
  float* denom = (float*)(ws + (size_t)N_ROWS * ROWB);         // 8192 f32
  float* pos   = denom + N_ROWS;
  float* selfd = pos + N_ROWS;

  normpos_k<<<N_HALF, 256, 0, stream>>>(xi, xj, zq, pos, selfd, denom);
  simexp_k<<<NG1 + NG2, 512, 0, stream>>>(zq, denom);
  loss_k<<<1, 256, 0, stream>>>(denom, pos, selfd, out);
}

// Round 19
// 128.225 us; speedup vs baseline: 1.0676x; 1.0676x over previous
//
#include <hip/hip_runtime.h>
#include <hip/hip_bf16.h>

#define N_ROWS 8192
#define N_HALF 4096
#define DIM    2048
#define ROWB   2048       // bytes per z row (fp8, K-INTERLEAVED)
#define INV_T  2.0f
#define QSCL   64.0f      // z scaled by 64 before fp8 quant
#define SIMSCL 0.00048828125f  // INV_T / (QSCL*QSCL) = 2/4096
#define NG1    1024       // full tiles: sum_{bi}(63-2*bi), bj in [2bi,63)
#define NG2    256        // tail: 32 bj=63 tiles M-split x8
#define NKT    32         // DIM/64 K-tiles

typedef __attribute__((ext_vector_type(4))) float f32x4;
typedef __attribute__((ext_vector_type(2))) long lx2;

__device__ __forceinline__ void gload_lds16(const void* g, void* l) {
  __builtin_amdgcn_global_load_lds(
      (const __attribute__((address_space(1))) unsigned int*)g,
      (__attribute__((address_space(3))) unsigned int*)l, 16, 0, 0);
}

// ---------------------------------------------------------------------------
// Kernel 1 (r17 verbatim): normalize + fp8-quantize + pos + self + denom=0.
// zq K-INTERLEAVED: k at byte (k>>6)*64 + ((k>>3)&3)*16 + ((k>>5)&1)*8 + (k&7)
// ---------------------------------------------------------------------------
__global__ __launch_bounds__(256) void normpos_k(
    const float* __restrict__ xi, const float* __restrict__ xj,
    char* __restrict__ zq, float* __restrict__ pos,
    float* __restrict__ selfd, float* __restrict__ denom)
{
  const int b = blockIdx.x;            // 0..4095
  const int t = threadIdx.x;
  const float4* si = (const float4*)(xi + (size_t)b * DIM);
  const float4* sj = (const float4*)(xj + (size_t)b * DIM);
  float4 a0 = si[t * 2], a1 = si[t * 2 + 1];
  float4 c0 = sj[t * 2], c1 = sj[t * 2 + 1];
  float ssi = a0.x*a0.x + a0.y*a0.y + a0.z*a0.z + a0.w*a0.w
            + a1.x*a1.x + a1.y*a1.y + a1.z*a1.z + a1.w*a1.w;
  float ssj = c0.x*c0.x + c0.y*c0.y + c0.z*c0.z + c0.w*c0.w
            + c1.x*c1.x + c1.y*c1.y + c1.z*c1.z + c1.w*c1.w;
  #pragma unroll
  for (int m = 1; m < 64; m <<= 1) {
    ssi += __shfl_xor(ssi, m, 64);
    ssj += __shfl_xor(ssj, m, 64);
  }
  __shared__ float ri[4], rj[4];
  if ((t & 63) == 0) { ri[t >> 6] = ssi; rj[t >> 6] = ssj; }
  __syncthreads();
  float sci = 1.0f / fmaxf(sqrtf(ri[0] + ri[1] + ri[2] + ri[3]), 1e-12f);
  float scj = 1.0f / fmaxf(sqrtf(rj[0] + rj[1] + rj[2] + rj[3]), 1e-12f);

  float fi[8] = {a0.x, a0.y, a0.z, a0.w, a1.x, a1.y, a1.z, a1.w};
  float fj[8] = {c0.x, c0.y, c0.z, c0.w, c1.x, c1.y, c1.z, c1.w};
  float ni[8], nj[8];
  float dp = 0.f;
  #pragma unroll
  for (int e = 0; e < 8; ++e) {
    ni[e] = fi[e] * sci;
    nj[e] = fj[e] * scj;
    dp += ni[e] * nj[e];                 // fp32 positive-pair sim
  }
  int wi0 = 0, wi1 = 0, wj0 = 0, wj1 = 0;
  wi0 = __builtin_amdgcn_cvt_pk_fp8_f32(ni[0]*QSCL, ni[1]*QSCL, wi0, false);
  wi0 = __builtin_amdgcn_cvt_pk_fp8_f32(ni[2]*QSCL, ni[3]*QSCL, wi0, true);
  wi1 = __builtin_amdgcn_cvt_pk_fp8_f32(ni[4]*QSCL, ni[5]*QSCL, wi1, false);
  wi1 = __builtin_amdgcn_cvt_pk_fp8_f32(ni[6]*QSCL, ni[7]*QSCL, wi1, true);
  wj0 = __builtin_amdgcn_cvt_pk_fp8_f32(nj[0]*QSCL, nj[1]*QSCL, wj0, false);
  wj0 = __builtin_amdgcn_cvt_pk_fp8_f32(nj[2]*QSCL, nj[3]*QSCL, wj0, true);
  wj1 = __builtin_amdgcn_cvt_pk_fp8_f32(nj[4]*QSCL, nj[5]*QSCL, wj1, false);
  wj1 = __builtin_amdgcn_cvt_pk_fp8_f32(nj[6]*QSCL, nj[7]*QSCL, wj1, true);

  const size_t ipos = (size_t)(t >> 3) * 64 + (t & 3) * 16 + ((t >> 2) & 1) * 8;
  *(int2*)(zq + (size_t)b * ROWB + ipos)            = make_int2(wi0, wi1);
  *(int2*)(zq + (size_t)(b + N_HALF) * ROWB + ipos) = make_int2(wj0, wj1);

  float dsi = 0.f, dsj = 0.f;
  {
    float d;
    d = __builtin_amdgcn_cvt_f32_fp8(wi0, 0); dsi += d * d;
    d = __builtin_amdgcn_cvt_f32_fp8(wi0, 1); dsi += d * d;
    d = __builtin_amdgcn_cvt_f32_fp8(wi0, 2); dsi += d * d;
    d = __builtin_amdgcn_cvt_f32_fp8(wi0, 3); dsi += d * d;
    d = __builtin_amdgcn_cvt_f32_fp8(wi1, 0); dsi += d * d;
    d = __builtin_amdgcn_cvt_f32_fp8(wi1, 1); dsi += d * d;
    d = __builtin_amdgcn_cvt_f32_fp8(wi1, 2); dsi += d * d;
    d = __builtin_amdgcn_cvt_f32_fp8(wi1, 3); dsi += d * d;
    d = __builtin_amdgcn_cvt_f32_fp8(wj0, 0); dsj += d * d;
    d = __builtin_amdgcn_cvt_f32_fp8(wj0, 1); dsj += d * d;
    d = __builtin_amdgcn_cvt_f32_fp8(wj0, 2); dsj += d * d;
    d = __builtin_amdgcn_cvt_f32_fp8(wj0, 3); dsj += d * d;
    d = __builtin_amdgcn_cvt_f32_fp8(wj1, 0); dsj += d * d;
    d = __builtin_amdgcn_cvt_f32_fp8(wj1, 1); dsj += d * d;
    d = __builtin_amdgcn_cvt_f32_fp8(wj1, 2); dsj += d * d;
    d = __builtin_amdgcn_cvt_f32_fp8(wj1, 3); dsj += d * d;
  }
  #pragma unroll
  for (int m = 1; m < 64; m <<= 1) {
    dp  += __shfl_xor(dp, m, 64);
    dsi += __shfl_xor(dsi, m, 64);
    dsj += __shfl_xor(dsj, m, 64);
  }
  __shared__ float rp[4], rsi[4], rsj[4];
  if ((t & 63) == 0) { rp[t >> 6] = dp; rsi[t >> 6] = dsi; rsj[t >> 6] = dsj; }
  __syncthreads();
  if (t == 0) {
    float p = rp[0] + rp[1] + rp[2] + rp[3];
    pos[b]            = p;
    pos[b + N_HALF]   = p;
    selfd[b]          = rsi[0] + rsi[1] + rsi[2] + rsi[3];
    selfd[b + N_HALF] = rsj[0] + rsj[1] + rsj[2] + rsj[3];
    denom[b]          = 0.f;
    denom[b + N_HALF] = 0.f;
  }
}

// ---------------------------------------------------------------------------
// Kernel 2: fp8 symmetric fused sim-tile + exp row/col sums, BK=64 —
// r17 template with 4 WAVES x 128x64 per wave (a[8] x b[4], 64 MFMA/phase):
// per-CU phase reads drop 128 -> 96 b128 (FLOP unchanged) — the binding
// LDS-read term shrinks 25%.  256-thread blocks, 2 blk/CU (72 KiB LDS).
// STAGE = 6 gload_lds16 calls (A x4, B x2, 4 KiB each) -> steady vmcnt(6).
// Same conflict-free interleaved-b128 layout and swizzle as r17:
// LDS row q (128 B) = tile rows 2q,2q+1; 16B slot s = ((r&1)*4+o)^(q&7).
// ---------------------------------------------------------------------------
__global__ __launch_bounds__(256, 2) void simexp_k(
    const char* __restrict__ zq, float* __restrict__ denom)
{
  __shared__ char lds[73728];
  char* ldsA = lds;            // 3 x 16384 (tail: 3 x 2048)
  char* ldsB = lds + 49152;    // 3 x 8192

  const int t    = threadIdx.x;
  const int wave = t >> 6, lane = t & 63;
  const int o    = lane >> 4;          // k-octet 0..3
  const int bid  = blockIdx.x;

  // staging-source decomposition (inverse of linear LDS dest):
  // one 4 KiB call = 256 thr x 16B = 32 LDS rows (q = t>>3) = 64 tile rows.
  const int sqq = t >> 3;              // 0..31
  const int s0  = (t & 7) ^ (sqq & 7);
  const int srr = s0 >> 2;             // row parity
  const int so  = s0 & 3;              // octet-pair index

  if (bid < NG1) {
    // ===================== FULL 256x128 TILE PATH ========================
    const int wr = wave >> 1, wc = wave & 1;   // 2M x 2N, per-wave 128x64

    int rem = (bid & 7) * (NG1 / 8) + (bid >> 3);   // XCD-bijective
    int bi = 0;
    while (rem >= 63 - 2 * bi) { rem -= 63 - 2 * bi; ++bi; }
    const int bj   = 2 * bi + rem;               // in [2bi, 63)
    const int row0 = bi * 256;
    const int col0 = bj * 128;

    // call g covers tile rows g*64 .. g*64+63
    const char* srcA = zq + (size_t)(row0 + 2 * sqq + srr) * ROWB + so * 16;
    const char* srcB = zq + (size_t)(col0 + 2 * sqq + srr) * ROWB + so * 16;
    char* dA = ldsA + wave * 1024;
    char* dB = ldsB + wave * 1024;

    int offA[8], offB[4];
    #pragma unroll
    for (int m = 0; m < 8; ++m) {
      int r = wr * 128 + m * 16 + (lane & 15);
      int q = r >> 1;
      offA[m] = q * 128 + ((((r & 1) * 4 + o) ^ (q & 7)) << 4);
    }
    #pragma unroll
    for (int n = 0; n < 4; ++n) {
      int r = wc * 64 + n * 16 + (lane & 15);
      int q = r >> 1;
      offB[n] = q * 128 + ((((r & 1) * 4 + o) ^ (q & 7)) << 4);
    }

    f32x4 acc[8][4] = {};

#define STAGE(kt, slot) do {                                              \
      gload_lds16(srcA + (kt) * 64,                        dA + (slot) * 16384);          \
      gload_lds16(srcA + (kt) * 64 + (size_t) 64 * ROWB,   dA + (slot) * 16384 + 4096);   \
      gload_lds16(srcA + (kt) * 64 + (size_t)128 * ROWB,   dA + (slot) * 16384 + 8192);   \
      gload_lds16(srcA + (kt) * 64 + (size_t)192 * ROWB,   dA + (slot) * 16384 + 12288);  \
      gload_lds16(srcB + (kt) * 64,                        dB + (slot) * 8192);           \
      gload_lds16(srcB + (kt) * 64 + (size_t) 64 * ROWB,   dB + (slot) * 8192 + 4096);    \
    } while (0)

    STAGE(0, 0);
    STAGE(1, 1);

    int sl = 0;
    for (int p = 0; p < NKT; ++p) {
      if (p < NKT - 1) asm volatile("s_waitcnt vmcnt(6)" ::: "memory");
      else             asm volatile("s_waitcnt vmcnt(0)" ::: "memory");
      __builtin_amdgcn_s_barrier();
      __builtin_amdgcn_sched_barrier(0);

      const char* Ab = ldsA + sl * 16384;
      const char* Bb = ldsB + sl * 8192;
      lx2 a[8], b[4];
      #pragma unroll
      for (int m = 0; m < 8; ++m) a[m] = *(const lx2*)(Ab + offA[m]);
      #pragma unroll
      for (int n = 0; n < 4; ++n) b[n] = *(const lx2*)(Bb + offB[n]);

      if (p + 2 < NKT) {
        int s2 = sl + 2; if (s2 >= 3) s2 -= 3;
        STAGE(p + 2, s2);
      }

      __builtin_amdgcn_s_setprio(1);
      #pragma unroll
      for (int m = 0; m < 8; ++m)
        #pragma unroll
        for (int n = 0; n < 4; ++n)
          acc[m][n] = __builtin_amdgcn_mfma_f32_16x16x32_fp8_fp8(
              a[m][0], b[n][0], acc[m][n], 0, 0, 0);
      #pragma unroll
      for (int m = 0; m < 8; ++m)
        #pragma unroll
        for (int n = 0; n < 4; ++n)
          acc[m][n] = __builtin_amdgcn_mfma_f32_16x16x32_fp8_fp8(
              a[m][1], b[n][1], acc[m][n], 0, 0, 0);
      __builtin_amdgcn_s_setprio(0);
      __builtin_amdgcn_sched_barrier(0);

      if (++sl >= 3) sl = 0;
    }
#undef STAGE

    #pragma unroll
    for (int m = 0; m < 8; ++m)
      #pragma unroll
      for (int n = 0; n < 4; ++n)
        #pragma unroll
        for (int r = 0; r < 4; ++r)
          acc[m][n][r] = __expf(acc[m][n][r] * SIMSCL);

    // row sums: C layout col = lane&15, row = (lane>>4)*4 + reg
    #pragma unroll
    for (int m = 0; m < 8; ++m) {
      #pragma unroll
      for (int r = 0; r < 4; ++r) {
        float s = acc[m][0][r] + acc[m][1][r] + acc[m][2][r] + acc[m][3][r];
        s += __shfl_xor(s, 1, 64);
        s += __shfl_xor(s, 2, 64);
        s += __shfl_xor(s, 4, 64);
        s += __shfl_xor(s, 8, 64);
        if ((lane & 15) == 0) {
          int grow = row0 + wr * 128 + m * 16 + (lane >> 4) * 4 + r;
          atomicAdd(&denom[grow], s);
        }
      }
    }

    if (bj >= 2 * bi + 2) {
      #pragma unroll
      for (int n = 0; n < 4; ++n) {
        float cs = 0.f;
        #pragma unroll
        for (int m = 0; m < 8; ++m)
          #pragma unroll
          for (int r = 0; r < 4; ++r)
            cs += acc[m][n][r];
        cs += __shfl_xor(cs, 16, 64);
        cs += __shfl_xor(cs, 32, 64);
        if ((lane >> 4) == 0) {
          int gcol = col0 + wc * 64 + n * 16 + (lane & 15);
          atomicAdd(&denom[gcol], cs);
        }
      }
    }
  } else {
    // ===================== TAIL PATH: 32-row x 128-col, cols 8064 ========
    const int sub  = bid - NG1;                // 0..255
    const int bi   = sub >> 3;                 // band 0..31
    const int row0 = bi * 256 + (sub & 7) * 32;
    const int col0 = 8064;

    const char* srcB = zq + (size_t)(col0 + 2 * sqq + srr) * ROWB + so * 16;
    // A: 2 KiB staged by waves 0-1 (t<128): q = (t&127)>>3 in 0..15
    const int tA   = t & 127;
    const int sqA  = tA >> 3;
    const int s0A  = (tA & 7) ^ (sqA & 7);
    const char* srcAs = zq + (size_t)(row0 + 2 * sqA + (s0A >> 2)) * ROWB
                      + (s0A & 3) * 16;

    // per-wave 32 rows x 32 cols: a 2 frags, b 2 frags (cols wave*32..)
    int offA2[2], offB2[2];
    #pragma unroll
    for (int m = 0; m < 2; ++m) {
      int r = m * 16 + (lane & 15);            // 0..31
      int q = r >> 1;
      offA2[m] = q * 128 + ((((r & 1) * 4 + o) ^ (q & 7)) << 4);
    }
    #pragma unroll
    for (int n = 0; n < 2; ++n) {
      int r = wave * 32 + n * 16 + (lane & 15); // 0..127
      int q = r >> 1;
      offB2[n] = q * 128 + ((((r & 1) * 4 + o) ^ (q & 7)) << 4);
    }

    f32x4 acc2[2][2] = {};

#define STAGE_T(kt, slot) do {                                            \
      gload_lds16(srcB + (kt) * 64,                      ldsB + (slot) * 8192 + wave * 1024);        \
      gload_lds16(srcB + (kt) * 64 + (size_t)64 * ROWB,  ldsB + (slot) * 8192 + 4096 + wave * 1024); \
      if (wave < 2)                                                       \
        gload_lds16(srcAs + (kt) * 64,                                    \
                    ldsA + (slot) * 2048 + wave * 1024);                  \
    } while (0)

    STAGE_T(0, 0);
    STAGE_T(1, 1);

    int sl = 0;
    for (int p = 0; p < NKT; ++p) {
      if (p < NKT - 1) {
        if (wave < 2) asm volatile("s_waitcnt vmcnt(3)" ::: "memory");
        else          asm volatile("s_waitcnt vmcnt(2)" ::: "memory");
      } else {
        asm volatile("s_waitcnt vmcnt(0)" ::: "memory");
      }
      __builtin_amdgcn_s_barrier();
      __builtin_amdgcn_sched_barrier(0);

      const char* Ab = ldsA + sl * 2048;
      const char* Bb = ldsB + sl * 8192;
      lx2 a0 = *(const lx2*)(Ab + offA2[0]);
      lx2 a1 = *(const lx2*)(Ab + offA2[1]);
      lx2 b0 = *(const lx2*)(Bb + offB2[0]);
      lx2 b1 = *(const lx2*)(Bb + offB2[1]);

      if (p + 2 < NKT) {
        int s2 = sl + 2; if (s2 >= 3) s2 -= 3;
        STAGE_T(p + 2, s2);
      }

      __builtin_amdgcn_s_setprio(1);
      acc2[0][0] = __builtin_amdgcn_mfma_f32_16x16x32_fp8_fp8(a0[0], b0[0], acc2[0][0], 0, 0, 0);
      acc2[0][1] = __builtin_amdgcn_mfma_f32_16x16x32_fp8_fp8(a0[0], b1[0], acc2[0][1], 0, 0, 0);
      acc2[1][0] = __builtin_amdgcn_mfma_f32_16x16x32_fp8_fp8(a1[0], b0[0], acc2[1][0], 0, 0, 0);
      acc2[1][1] = __builtin_amdgcn_mfma_f32_16x16x32_fp8_fp8(a1[0], b1[0], acc2[1][1], 0, 0, 0);
      acc2[0][0] = __builtin_amdgcn_mfma_f32_16x16x32_fp8_fp8(a0[1], b0[1], acc2[0][0], 0, 0, 0);
      acc2[0][1] = __builtin_amdgcn_mfma_f32_16x16x32_fp8_fp8(a0[1], b1[1], acc2[0][1], 0, 0, 0);
      acc2[1][0] = __builtin_amdgcn_mfma_f32_16x16x32_fp8_fp8(a1[1], b0[1], acc2[1][0], 0, 0, 0);
      acc2[1][1] = __builtin_amdgcn_mfma_f32_16x16x32_fp8_fp8(a1[1], b1[1], acc2[1][1], 0, 0, 0);
      __builtin_amdgcn_s_setprio(0);
      __builtin_amdgcn_sched_barrier(0);

      if (++sl >= 3) sl = 0;
    }
#undef STAGE_T

    #pragma unroll
    for (int m = 0; m < 2; ++m)
      #pragma unroll
      for (int n = 0; n < 2; ++n)
        #pragma unroll
        for (int r = 0; r < 4; ++r)
          acc2[m][n][r] = __expf(acc2[m][n][r] * SIMSCL);

    // row sums: each wave's 32-col slice, atomic-accumulated per row
    #pragma unroll
    for (int m = 0; m < 2; ++m) {
      #pragma unroll
      for (int r = 0; r < 4; ++r) {
        float s = acc2[m][0][r] + acc2[m][1][r];
        s += __shfl_xor(s, 1, 64);
        s += __shfl_xor(s, 2, 64);
        s += __shfl_xor(s, 4, 64);
        s += __shfl_xor(s, 8, 64);
        if ((lane & 15) == 0) {
          int grow = row0 + m * 16 + (lane >> 4) * 4 + r;
          atomicAdd(&denom[grow], s);
        }
      }
    }

    // col sums — strip right of band diag for bi <= 30
    if (bi <= 30) {
      #pragma unroll
      for (int n = 0; n < 2; ++n) {
        float cs = 0.f;
        #pragma unroll
        for (int m = 0; m < 2; ++m)
          #pragma unroll
          for (int r = 0; r < 4; ++r)
            cs += acc2[m][n][r];
        cs += __shfl_xor(cs, 16, 64);
        cs += __shfl_xor(cs, 32, 64);
        if ((lane >> 4) == 0) {
          int gcol = col0 + wave * 32 + n * 16 + (lane & 15);
          atomicAdd(&denom[gcol], cs);
        }
      }
    }
  }
}

// ---------------------------------------------------------------------------
// Kernel 3: loss = mean_i( log(denom_i - exp(self_i*SIMSCL)) - pos_i*INV_T )
// ---------------------------------------------------------------------------
__global__ __launch_bounds__(256) void loss_k(
    const float* __restrict__ denom, const float* __restrict__ pos,
    const float* __restrict__ selfd, float* __restrict__ out)
{
  const int t = threadIdx.x;
  float acc = 0.f;
  for (int i = t; i < N_ROWS; i += 256) {
    float d = denom[i] - __expf(selfd[i] * SIMSCL);
    acc += __logf(d) - pos[i] * INV_T;
  }
  #pragma unroll
  for (int m = 1; m < 64; m <<= 1) acc += __shfl_xor(acc, m, 64);
  __shared__ float red[4];
  if ((t & 63) == 0) red[t >> 6] = acc;
  __syncthreads();
  if (t == 0) out[0] = (red[0] + red[1] + red[2] + red[3]) / (float)N_ROWS;
}

// ---------------------------------------------------------------------------
extern "C" void kernel_launch(void* const* d_in, const int* in_sizes, int n_in,
                              void* d_out, int out_size, void* d_ws, size_t ws_size,
                              hipStream_t stream) {
  const float* xi = (const float*)d_in[0];
  const float* xj = (const float*)d_in[1];
  float* out = (float*)d_out;

  char*  ws    = (char*)d_ws;
  char*  zq    = ws;                                           // 16 MiB fp8 z
  float* denom = (float*)(ws + (size_t)N_ROWS * ROWB);         // 8192 f32
  float* pos   = denom + N_ROWS;
  float* selfd = pos + N_ROWS;

  normpos_k<<<N_HALF, 256, 0, stream>>>(xi, xj, zq, pos, selfd, denom);
  simexp_k<<<NG1 + NG2, 256, 0, stream>>>(zq, denom);
  loss_k<<<1, 256, 0, stream>>>(denom, pos, selfd, out);
}

// Round 20
// 119.605 us; speedup vs baseline: 1.1445x; 1.0721x over previous
//
#include <hip/hip_runtime.h>
#include <hip/hip_bf16.h>

#define N_ROWS 8192
#define N_HALF 4096
#define DIM    2048
#define ROWB   2048       // bytes per z row (fp8, K-INTERLEAVED)
#define INV_T  2.0f
#define QSCL   64.0f      // z scaled by 64 before fp8 quant
#define SIMSCL 0.00048828125f  // INV_T / (QSCL*QSCL) = 2/4096
#define NG1    1024       // full tiles: sum_{bi}(63-2*bi), bj in [2bi,63)
#define NG2    256        // tail: 32 bj=63 tiles M-split x8
#define NKT    32         // DIM/64 K-tiles

typedef __attribute__((ext_vector_type(4))) float f32x4;
typedef __attribute__((ext_vector_type(2))) long lx2;

__device__ __forceinline__ void gload_lds16(const void* g, void* l) {
  __builtin_amdgcn_global_load_lds(
      (const __attribute__((address_space(1))) unsigned int*)g,
      (__attribute__((address_space(3))) unsigned int*)l, 16, 0, 0);
}

// ---------------------------------------------------------------------------
// Kernel 1 (r17 verbatim): normalize + fp8-quantize + pos + self + denom=0.
// zq K-INTERLEAVED: k at byte (k>>6)*64 + ((k>>3)&3)*16 + ((k>>5)&1)*8 + (k&7)
// ---------------------------------------------------------------------------
__global__ __launch_bounds__(256) void normpos_k(
    const float* __restrict__ xi, const float* __restrict__ xj,
    char* __restrict__ zq, float* __restrict__ pos,
    float* __restrict__ selfd, float* __restrict__ denom)
{
  const int b = blockIdx.x;            // 0..4095
  const int t = threadIdx.x;
  const float4* si = (const float4*)(xi + (size_t)b * DIM);
  const float4* sj = (const float4*)(xj + (size_t)b * DIM);
  float4 a0 = si[t * 2], a1 = si[t * 2 + 1];
  float4 c0 = sj[t * 2], c1 = sj[t * 2 + 1];
  float ssi = a0.x*a0.x + a0.y*a0.y + a0.z*a0.z + a0.w*a0.w
            + a1.x*a1.x + a1.y*a1.y + a1.z*a1.z + a1.w*a1.w;
  float ssj = c0.x*c0.x + c0.y*c0.y + c0.z*c0.z + c0.w*c0.w
            + c1.x*c1.x + c1.y*c1.y + c1.z*c1.z + c1.w*c1.w;
  #pragma unroll
  for (int m = 1; m < 64; m <<= 1) {
    ssi += __shfl_xor(ssi, m, 64);
    ssj += __shfl_xor(ssj, m, 64);
  }
  __shared__ float ri[4], rj[4];
  if ((t & 63) == 0) { ri[t >> 6] = ssi; rj[t >> 6] = ssj; }
  __syncthreads();
  float sci = 1.0f / fmaxf(sqrtf(ri[0] + ri[1] + ri[2] + ri[3]), 1e-12f);
  float scj = 1.0f / fmaxf(sqrtf(rj[0] + rj[1] + rj[2] + rj[3]), 1e-12f);

  float fi[8] = {a0.x, a0.y, a0.z, a0.w, a1.x, a1.y, a1.z, a1.w};
  float fj[8] = {c0.x, c0.y, c0.z, c0.w, c1.x, c1.y, c1.z, c1.w};
  float ni[8], nj[8];
  float dp = 0.f;
  #pragma unroll
  for (int e = 0; e < 8; ++e) {
    ni[e] = fi[e] * sci;
    nj[e] = fj[e] * scj;
    dp += ni[e] * nj[e];                 // fp32 positive-pair sim
  }
  int wi0 = 0, wi1 = 0, wj0 = 0, wj1 = 0;
  wi0 = __builtin_amdgcn_cvt_pk_fp8_f32(ni[0]*QSCL, ni[1]*QSCL, wi0, false);
  wi0 = __builtin_amdgcn_cvt_pk_fp8_f32(ni[2]*QSCL, ni[3]*QSCL, wi0, true);
  wi1 = __builtin_amdgcn_cvt_pk_fp8_f32(ni[4]*QSCL, ni[5]*QSCL, wi1, false);
  wi1 = __builtin_amdgcn_cvt_pk_fp8_f32(ni[6]*QSCL, ni[7]*QSCL, wi1, true);
  wj0 = __builtin_amdgcn_cvt_pk_fp8_f32(nj[0]*QSCL, nj[1]*QSCL, wj0, false);
  wj0 = __builtin_amdgcn_cvt_pk_fp8_f32(nj[2]*QSCL, nj[3]*QSCL, wj0, true);
  wj1 = __builtin_amdgcn_cvt_pk_fp8_f32(nj[4]*QSCL, nj[5]*QSCL, wj1, false);
  wj1 = __builtin_amdgcn_cvt_pk_fp8_f32(nj[6]*QSCL, nj[7]*QSCL, wj1, true);

  const size_t ipos = (size_t)(t >> 3) * 64 + (t & 3) * 16 + ((t >> 2) & 1) * 8;
  *(int2*)(zq + (size_t)b * ROWB + ipos)            = make_int2(wi0, wi1);
  *(int2*)(zq + (size_t)(b + N_HALF) * ROWB + ipos) = make_int2(wj0, wj1);

  float dsi = 0.f, dsj = 0.f;
  {
    float d;
    d = __builtin_amdgcn_cvt_f32_fp8(wi0, 0); dsi += d * d;
    d = __builtin_amdgcn_cvt_f32_fp8(wi0, 1); dsi += d * d;
    d = __builtin_amdgcn_cvt_f32_fp8(wi0, 2); dsi += d * d;
    d = __builtin_amdgcn_cvt_f32_fp8(wi0, 3); dsi += d * d;
    d = __builtin_amdgcn_cvt_f32_fp8(wi1, 0); dsi += d * d;
    d = __builtin_amdgcn_cvt_f32_fp8(wi1, 1); dsi += d * d;
    d = __builtin_amdgcn_cvt_f32_fp8(wi1, 2); dsi += d * d;
    d = __builtin_amdgcn_cvt_f32_fp8(wi1, 3); dsi += d * d;
    d = __builtin_amdgcn_cvt_f32_fp8(wj0, 0); dsj += d * d;
    d = __builtin_amdgcn_cvt_f32_fp8(wj0, 1); dsj += d * d;
    d = __builtin_amdgcn_cvt_f32_fp8(wj0, 2); dsj += d * d;
    d = __builtin_amdgcn_cvt_f32_fp8(wj0, 3); dsj += d * d;
    d = __builtin_amdgcn_cvt_f32_fp8(wj1, 0); dsj += d * d;
    d = __builtin_amdgcn_cvt_f32_fp8(wj1, 1); dsj += d * d;
    d = __builtin_amdgcn_cvt_f32_fp8(wj1, 2); dsj += d * d;
    d = __builtin_amdgcn_cvt_f32_fp8(wj1, 3); dsj += d * d;
  }
  #pragma unroll
  for (int m = 1; m < 64; m <<= 1) {
    dp  += __shfl_xor(dp, m, 64);
    dsi += __shfl_xor(dsi, m, 64);
    dsj += __shfl_xor(dsj, m, 64);
  }
  __shared__ float rp[4], rsi[4], rsj[4];
  if ((t & 63) == 0) { rp[t >> 6] = dp; rsi[t >> 6] = dsi; rsj[t >> 6] = dsj; }
  __syncthreads();
  if (t == 0) {
    float p = rp[0] + rp[1] + rp[2] + rp[3];
    pos[b]            = p;
    pos[b + N_HALF]   = p;
    selfd[b]          = rsi[0] + rsi[1] + rsi[2] + rsi[3];
    selfd[b + N_HALF] = rsj[0] + rsj[1] + rsj[2] + rsj[3];
    denom[b]          = 0.f;
    denom[b + N_HALF] = 0.f;
  }
}

// ---------------------------------------------------------------------------
// Kernel 2 (r17 verbatim): fp8 symmetric fused sim-tile + exp row/col sums,
// BK=64, interleaved-b128 conflict-free reads, 8 waves (4M x 2N) x 64x64.
// Grid: 1024 full 256x128 tiles (2 clean rounds, 2 blk/CU) + 256 M-split
// tail.  3-slot LDS rotation lead-2 (A 16K + B 8K = 72 KiB), STAGE = 3
// uniform calls/wave -> steady vmcnt(3), final vmcnt(0).
// LDS row q (128 B) = tile rows 2q,2q+1; 16B slot s = ((r&1)*4+o)^(q&7).
// ---------------------------------------------------------------------------
__global__ __launch_bounds__(512, 4) void simexp_k(
    const char* __restrict__ zq, float* __restrict__ denom)
{
  __shared__ char lds[73728];
  char* ldsA = lds;            // 3 x 16384 (tail: 3 x 2048)
  char* ldsB = lds + 49152;    // 3 x 8192

  const int t    = threadIdx.x;
  const int wave = t >> 6, lane = t & 63;
  const int o    = lane >> 4;          // k-octet 0..3
  const int bid  = blockIdx.x;

  const int sqq = t >> 3;              // 0..63
  const int s0  = (t & 7) ^ (sqq & 7);
  const int srr = s0 >> 2;             // row parity
  const int so  = s0 & 3;              // octet-pair index

  if (bid < NG1) {
    // ===================== FULL 256x128 TILE PATH ========================
    const int wr = wave >> 1, wc = wave & 1;   // 4M x 2N

    int rem = (bid & 7) * (NG1 / 8) + (bid >> 3);   // XCD-bijective
    int bi = 0;
    while (rem >= 63 - 2 * bi) { rem -= 63 - 2 * bi; ++bi; }
    const int bj   = 2 * bi + rem;               // in [2bi, 63)
    const int row0 = bi * 256;
    const int col0 = bj * 128;

    const char* srcA0 = zq + (size_t)(row0 + 2 * sqq + srr) * ROWB + so * 16;
    const char* srcA1 = srcA0 + (size_t)128 * ROWB;
    const char* srcB  = zq + (size_t)(col0 + 2 * sqq + srr) * ROWB + so * 16;
    char* dA = ldsA + wave * 1024;
    char* dB = ldsB + wave * 1024;

    int offA[4], offB[4];
    #pragma unroll
    for (int m = 0; m < 4; ++m) {
      int r = wr * 64 + m * 16 + (lane & 15);
      int q = r >> 1;
      offA[m] = q * 128 + ((((r & 1) * 4 + o) ^ (q & 7)) << 4);
    }
    #pragma unroll
    for (int n = 0; n < 4; ++n) {
      int r = wc * 64 + n * 16 + (lane & 15);
      int q = r >> 1;
      offB[n] = q * 128 + ((((r & 1) * 4 + o) ^ (q & 7)) << 4);
    }

    f32x4 acc[4][4] = {};

#define STAGE(kt, slot) do {                                   \
      gload_lds16(srcA0 + (kt) * 64, dA + (slot) * 16384);     \
      gload_lds16(srcA1 + (kt) * 64, dA + (slot) * 16384 + 8192); \
      gload_lds16(srcB  + (kt) * 64, dB + (slot) * 8192);      \
    } while (0)

    STAGE(0, 0);
    STAGE(1, 1);

    int sl = 0;
    for (int p = 0; p < NKT; ++p) {
      if (p < NKT - 1) asm volatile("s_waitcnt vmcnt(3)" ::: "memory");
      else             asm volatile("s_waitcnt vmcnt(0)" ::: "memory");
      __builtin_amdgcn_s_barrier();
      __builtin_amdgcn_sched_barrier(0);

      const char* Ab = ldsA + sl * 16384;
      const char* Bb = ldsB + sl * 8192;
      lx2 a[4], b[4];
      #pragma unroll
      for (int m = 0; m < 4; ++m) a[m] = *(const lx2*)(Ab + offA[m]);
      #pragma unroll
      for (int n = 0; n < 4; ++n) b[n] = *(const lx2*)(Bb + offB[n]);

      if (p + 2 < NKT) {
        int s2 = sl + 2; if (s2 >= 3) s2 -= 3;
        STAGE(p + 2, s2);
      }

      __builtin_amdgcn_s_setprio(1);
      #pragma unroll
      for (int m = 0; m < 4; ++m)
        #pragma unroll
        for (int n = 0; n < 4; ++n)
          acc[m][n] = __builtin_amdgcn_mfma_f32_16x16x32_fp8_fp8(
              a[m][0], b[n][0], acc[m][n], 0, 0, 0);
      #pragma unroll
      for (int m = 0; m < 4; ++m)
        #pragma unroll
        for (int n = 0; n < 4; ++n)
          acc[m][n] = __builtin_amdgcn_mfma_f32_16x16x32_fp8_fp8(
              a[m][1], b[n][1], acc[m][n], 0, 0, 0);
      __builtin_amdgcn_s_setprio(0);
      __builtin_amdgcn_sched_barrier(0);

      if (++sl >= 3) sl = 0;
    }
#undef STAGE

    #pragma unroll
    for (int m = 0; m < 4; ++m)
      #pragma unroll
      for (int n = 0; n < 4; ++n)
        #pragma unroll
        for (int r = 0; r < 4; ++r)
          acc[m][n][r] = __expf(acc[m][n][r] * SIMSCL);

    // row sums: C layout col = lane&15, row = (lane>>4)*4 + reg
    #pragma unroll
    for (int m = 0; m < 4; ++m) {
      #pragma unroll
      for (int r = 0; r < 4; ++r) {
        float s = acc[m][0][r] + acc[m][1][r] + acc[m][2][r] + acc[m][3][r];
        s += __shfl_xor(s, 1, 64);
        s += __shfl_xor(s, 2, 64);
        s += __shfl_xor(s, 4, 64);
        s += __shfl_xor(s, 8, 64);
        if ((lane & 15) == 0) {
          int grow = row0 + wr * 64 + m * 16 + (lane >> 4) * 4 + r;
          atomicAdd(&denom[grow], s);
        }
      }
    }

    if (bj >= 2 * bi + 2) {
      #pragma unroll
      for (int n = 0; n < 4; ++n) {
        float cs = 0.f;
        #pragma unroll
        for (int m = 0; m < 4; ++m)
          #pragma unroll
          for (int r = 0; r < 4; ++r)
            cs += acc[m][n][r];
        cs += __shfl_xor(cs, 16, 64);
        cs += __shfl_xor(cs, 32, 64);
        if ((lane >> 4) == 0) {
          int gcol = col0 + wc * 64 + n * 16 + (lane & 15);
          atomicAdd(&denom[gcol], cs);
        }
      }
    }
  } else {
    // ===================== TAIL PATH: 32-row x 128-col, cols 8064 ========
    const int sub  = bid - NG1;                // 0..255
    const int bi   = sub >> 3;                 // band 0..31
    const int row0 = bi * 256 + (sub & 7) * 32;
    const int col0 = 8064;

    const char* srcB = zq + (size_t)(col0 + 2 * sqq + srr) * ROWB + so * 16;
    const int tA   = t & 127;
    const int sqA  = tA >> 3;
    const int s0A  = (tA & 7) ^ (sqA & 7);
    const char* srcAs = zq + (size_t)(row0 + 2 * sqA + (s0A >> 2)) * ROWB
                      + (s0A & 3) * 16;

    int offA2[2], offB0;
    #pragma unroll
    for (int m = 0; m < 2; ++m) {
      int r = m * 16 + (lane & 15);            // 0..31
      int q = r >> 1;
      offA2[m] = q * 128 + ((((r & 1) * 4 + o) ^ (q & 7)) << 4);
    }
    {
      int r = wave * 16 + (lane & 15);         // 0..127
      int q = r >> 1;
      offB0 = q * 128 + ((((r & 1) * 4 + o) ^ (q & 7)) << 4);
    }

    f32x4 acc2[2] = {};

#define STAGE_T(kt, slot) do {                                            \
      gload_lds16(srcB + (kt) * 64, ldsB + (slot) * 8192 + wave * 1024);  \
      if (wave < 2)                                                       \
        gload_lds16(srcAs + (kt) * 64,                                    \
                    ldsA + (slot) * 2048 + wave * 1024);                  \
    } while (0)

    STAGE_T(0, 0);
    STAGE_T(1, 1);

    int sl = 0;
    for (int p = 0; p < NKT; ++p) {
      if (p < NKT - 1) {
        if (wave < 2) asm volatile("s_waitcnt vmcnt(2)" ::: "memory");
        else          asm volatile("s_waitcnt vmcnt(1)" ::: "memory");
      } else {
        asm volatile("s_waitcnt vmcnt(0)" ::: "memory");
      }
      __builtin_amdgcn_s_barrier();
      __builtin_amdgcn_sched_barrier(0);

      const char* Ab = ldsA + sl * 2048;
      const char* Bb = ldsB + sl * 8192;
      lx2 a0 = *(const lx2*)(Ab + offA2[0]);
      lx2 a1 = *(const lx2*)(Ab + offA2[1]);
      lx2 b0 = *(const lx2*)(Bb + offB0);

      if (p + 2 < NKT) {
        int s2 = sl + 2; if (s2 >= 3) s2 -= 3;
        STAGE_T(p + 2, s2);
      }

      __builtin_amdgcn_s_setprio(1);
      acc2[0] = __builtin_amdgcn_mfma_f32_16x16x32_fp8_fp8(a0[0], b0[0], acc2[0], 0, 0, 0);
      acc2[1] = __builtin_amdgcn_mfma_f32_16x16x32_fp8_fp8(a1[0], b0[0], acc2[1], 0, 0, 0);
      acc2[0] = __builtin_amdgcn_mfma_f32_16x16x32_fp8_fp8(a0[1], b0[1], acc2[0], 0, 0, 0);
      acc2[1] = __builtin_amdgcn_mfma_f32_16x16x32_fp8_fp8(a1[1], b0[1], acc2[1], 0, 0, 0);
      __builtin_amdgcn_s_setprio(0);
      __builtin_amdgcn_sched_barrier(0);

      if (++sl >= 3) sl = 0;
    }
#undef STAGE_T

    #pragma unroll
    for (int m = 0; m < 2; ++m)
      #pragma unroll
      for (int r = 0; r < 4; ++r)
        acc2[m][r] = __expf(acc2[m][r] * SIMSCL);

    #pragma unroll
    for (int m = 0; m < 2; ++m) {
      #pragma unroll
      for (int r = 0; r < 4; ++r) {
        float s = acc2[m][r];
        s += __shfl_xor(s, 1, 64);
        s += __shfl_xor(s, 2, 64);
        s += __shfl_xor(s, 4, 64);
        s += __shfl_xor(s, 8, 64);
        if ((lane & 15) == 0) {
          int grow = row0 + m * 16 + (lane >> 4) * 4 + r;
          atomicAdd(&denom[grow], s);
        }
      }
    }

    if (bi <= 30) {
      float cs = 0.f;
      #pragma unroll
      for (int m = 0; m < 2; ++m)
        #pragma unroll
        for (int r = 0; r < 4; ++r)
          cs += acc2[m][r];
      cs += __shfl_xor(cs, 16, 64);
      cs += __shfl_xor(cs, 32, 64);
      if ((lane >> 4) == 0) {
        int gcol = col0 + wave * 16 + (lane & 15);
        atomicAdd(&denom[gcol], cs);
      }
    }
  }
}

// ---------------------------------------------------------------------------
// Kernel 3: parallel loss — 32 blocks, fp32 atomic partials into zeroed out.
// loss = mean_i( log(denom_i - exp(self_i*SIMSCL)) - pos_i*INV_T )
// ---------------------------------------------------------------------------
__global__ __launch_bounds__(256) void loss_k(
    const float* __restrict__ denom, const float* __restrict__ pos,
    const float* __restrict__ selfd, float* __restrict__ out)
{
  const int i = blockIdx.x * 256 + threadIdx.x;   // one row per thread
  const int t = threadIdx.x;
  float d = denom[i] - __expf(selfd[i] * SIMSCL);
  float acc = __logf(d) - pos[i] * INV_T;
  #pragma unroll
  for (int m = 1; m < 64; m <<= 1) acc += __shfl_xor(acc, m, 64);
  __shared__ float red[4];
  if ((t & 63) == 0) red[t >> 6] = acc;
  __syncthreads();
  if (t == 0)
    atomicAdd(out, (red[0] + red[1] + red[2] + red[3]) * (1.0f / (float)N_ROWS));
}

// ---------------------------------------------------------------------------
extern "C" void kernel_launch(void* const* d_in, const int* in_sizes, int n_in,
                              void* d_out, int out_size, void* d_ws, size_t ws_size,
                              hipStream_t stream) {
  const float* xi = (const float*)d_in[0];
  const float* xj = (const float*)d_in[1];
  float* out = (float*)d_out;

  char*  ws    = (char*)d_ws;
  char*  zq    = ws;                                           // 16 MiB fp8 z
  float* denom = (float*)(ws + (size_t)N_ROWS * ROWB);         // 8192 f32
  float* pos   = denom + N_ROWS;
  float* selfd = pos + N_ROWS;

  hipMemsetAsync(out, 0, sizeof(float), stream);
  normpos_k<<<N_HALF, 256, 0, stream>>>(xi, xj, zq, pos, selfd, denom);
  simexp_k<<<NG1 + NG2, 512, 0, stream>>>(zq, denom);
  loss_k<<<N_ROWS / 256, 256, 0, stream>>>(denom, pos, selfd, out);
}